// Round 5
// baseline (466.306 us; speedup 1.0000x reference)
//
#include <hip/hip_runtime.h>
#include <hip/hip_bf16.h>
#include <math.h>

#define S_LEN 4096
#define EMB   1024
#define NHEAD 16
#define HDIM  64

typedef __attribute__((ext_vector_type(8))) short short8;
typedef __attribute__((ext_vector_type(4))) short short4_t;
typedef __attribute__((ext_vector_type(4))) float float4_t;
typedef unsigned short ushort_t;

#define GLOBAL_AS(p) ((const __attribute__((address_space(1))) void*)(p))
#define LDS_AS(p)    ((__attribute__((address_space(3))) void*)(p))

__device__ __forceinline__ unsigned short f2bf_rne(float f) {
    union { float f; unsigned int u; } v; v.f = f;
    unsigned int u = v.u;
    return (unsigned short)((u + 0x7FFF + ((u >> 16) & 1)) >> 16);
}
__device__ __forceinline__ float bfbits2f(unsigned short b) {
    union { unsigned int u; float f; } v; v.u = ((unsigned int)b) << 16;
    return v.f;
}

// ---------------------------------------------------------------------------
// split fp32 -> bf16 hi/lo planes (row-major, same layout)
// ---------------------------------------------------------------------------
__global__ __launch_bounds__(256) void split_x(
    const float* __restrict__ in, ushort_t* __restrict__ oh, ushort_t* __restrict__ ol)
{
    const int i = blockIdx.x * 256 + threadIdx.x;
    const float4_t v = ((const float4_t*)in)[i];
    short4_t h, l;
#pragma unroll
    for (int j = 0; j < 4; ++j) {
        unsigned short hb = f2bf_rne(v[j]);
        h[j] = (short)hb;
        l[j] = (short)f2bf_rne(v[j] - bfbits2f(hb));
    }
    ((short4_t*)oh)[i] = h;
    ((short4_t*)ol)[i] = l;
}

// ---------------------------------------------------------------------------
// transpose fp32 [R,C] -> bf16 [C,R] (hi, and lo if SPLIT)
// ---------------------------------------------------------------------------
template<bool SPLIT>
__global__ __launch_bounds__(256) void transpose_split(
    const float* __restrict__ in, ushort_t* __restrict__ oh, ushort_t* __restrict__ ol,
    int R, int C)
{
    __shared__ float t[64][65];
    const int r0 = blockIdx.y * 64, c0 = blockIdx.x * 64;
    for (int i = threadIdx.x; i < 64 * 64; i += 256) {
        int r = i >> 6, c = i & 63;
        t[r][c] = in[(size_t)(r0 + r) * C + c0 + c];
    }
    __syncthreads();
    for (int i = threadIdx.x; i < 64 * 64; i += 256) {
        int c = i >> 6, r = i & 63;
        float f = t[r][c];
        unsigned short hb = f2bf_rne(f);
        oh[(size_t)(c0 + c) * R + r0 + r] = hb;
        if constexpr (SPLIT)
            ol[(size_t)(c0 + c) * R + r0 + r] = f2bf_rne(f - bfbits2f(hb));
    }
}

// ---------------------------------------------------------------------------
// zero the work-queue counter (ws is poisoned 0xAA before every launch)
// ---------------------------------------------------------------------------
__global__ void zero_counter(unsigned int* c) {
    if (threadIdx.x == 0) *c = 0u;
}

// ---------------------------------------------------------------------------
// MFMA GEMM, m97 structure: 128x128 tile, BK=32, global_load_lds width 16.
// A [M,K] row-major bf16 (hi + optional lo); B^T [N,K] row-major bf16.
// SPLIT: acc = Ahi*Bhi + Ahi*Blo + Alo*Bhi (fp32-accurate product).
// EPI 0: C fp32 = acc + bias.   EPI 1 (QKV): cols<2048 -> qk hi/lo planes
// [4096,2048]; cols>=2048 -> V^T bf16 [1024,4096] (vt[(col-2048)*4096+row]).
// ---------------------------------------------------------------------------
template<bool SPLIT, int EPI>
__global__ __launch_bounds__(256) void gemm_mfma(
    const ushort_t* __restrict__ Ag, const ushort_t* __restrict__ Alg,
    const ushort_t* __restrict__ Bg, const ushort_t* __restrict__ Blg,
    const float* __restrict__ bias,
    float* __restrict__ C,
    ushort_t* __restrict__ qh, ushort_t* __restrict__ ql, ushort_t* __restrict__ vt,
    int M, int N, int K)
{
    constexpr int BK = 32;
    __shared__ ushort_t Ah[128 * BK];
    __shared__ ushort_t Bh[128 * BK];
    __shared__ ushort_t Al[SPLIT ? 128 * BK : 8];
    __shared__ ushort_t Bl[SPLIT ? 128 * BK : 8];

    const int tid = threadIdx.x;
    const int wave = tid >> 6, lane = tid & 63;
    const int l16 = lane & 15, quad = lane >> 4;
    const int wr = wave >> 1, wc = wave & 1;
    const int row0 = blockIdx.y * 128, col0 = blockIdx.x * 128;
    const int lrow = lane >> 2, lc8 = (lane & 3) * 8;

    float4_t acc[4][4];
#pragma unroll
    for (int i = 0; i < 4; ++i)
#pragma unroll
        for (int j = 0; j < 4; ++j) acc[i][j] = (float4_t){0.f, 0.f, 0.f, 0.f};

    for (int k0 = 0; k0 < K; k0 += BK) {
        __syncthreads();
#pragma unroll
        for (int i = 0; i < 2; ++i) {
            const int ar = i * 64 + wave * 16;
            __builtin_amdgcn_global_load_lds(
                GLOBAL_AS(Ag + (size_t)(row0 + ar + lrow) * K + k0 + lc8),
                LDS_AS(&Ah[ar * BK]), 16, 0, 0);
            __builtin_amdgcn_global_load_lds(
                GLOBAL_AS(Bg + (size_t)(col0 + ar + lrow) * K + k0 + lc8),
                LDS_AS(&Bh[ar * BK]), 16, 0, 0);
            if constexpr (SPLIT) {
                __builtin_amdgcn_global_load_lds(
                    GLOBAL_AS(Alg + (size_t)(row0 + ar + lrow) * K + k0 + lc8),
                    LDS_AS(&Al[ar * BK]), 16, 0, 0);
                __builtin_amdgcn_global_load_lds(
                    GLOBAL_AS(Blg + (size_t)(col0 + ar + lrow) * K + k0 + lc8),
                    LDS_AS(&Bl[ar * BK]), 16, 0, 0);
            }
        }
        __syncthreads();

        short8 af[4], bfr[4], afl[4], bfl[4];
#pragma unroll
        for (int t = 0; t < 4; ++t) {
            af[t]  = *(const short8*)&Ah[(wr * 64 + t * 16 + l16) * BK + quad * 8];
            bfr[t] = *(const short8*)&Bh[(wc * 64 + t * 16 + l16) * BK + quad * 8];
            if constexpr (SPLIT) {
                afl[t] = *(const short8*)&Al[(wr * 64 + t * 16 + l16) * BK + quad * 8];
                bfl[t] = *(const short8*)&Bl[(wc * 64 + t * 16 + l16) * BK + quad * 8];
            }
        }
#pragma unroll
        for (int i = 0; i < 4; ++i)
#pragma unroll
            for (int j = 0; j < 4; ++j) {
                acc[i][j] = __builtin_amdgcn_mfma_f32_16x16x32_bf16(af[i], bfr[j], acc[i][j], 0, 0, 0);
                if constexpr (SPLIT) {
                    acc[i][j] = __builtin_amdgcn_mfma_f32_16x16x32_bf16(af[i],  bfl[j], acc[i][j], 0, 0, 0);
                    acc[i][j] = __builtin_amdgcn_mfma_f32_16x16x32_bf16(afl[i], bfr[j], acc[i][j], 0, 0, 0);
                }
            }
    }

    // epilogue: C/D layout row=quad*4+r, col=l16
#pragma unroll
    for (int i = 0; i < 4; ++i) {
#pragma unroll
        for (int j = 0; j < 4; ++j) {
            const int colb = col0 + wc * 64 + j * 16 + l16;
            const float bv = bias[colb];
#pragma unroll
            for (int r = 0; r < 4; ++r) {
                const int row = row0 + wr * 64 + i * 16 + quad * 4 + r;
                const float val = acc[i][j][r] + bv;
                if constexpr (EPI == 0) {
                    C[(size_t)row * N + colb] = val;
                } else {
                    if (colb < 2048) {
                        unsigned short hb = f2bf_rne(val);
                        qh[(size_t)row * 2048 + colb] = hb;
                        ql[(size_t)row * 2048 + colb] = f2bf_rne(val - bfbits2f(hb));
                    } else {
                        // V^T: [d_global][s] — consecutive r -> contiguous
                        vt[(size_t)(colb - 2048) * 4096 + row] = f2bf_rne(val);
                    }
                }
            }
        }
    }
}

// ---------------------------------------------------------------------------
// MFMA causal flash attention — persistent work-queue version.
// 384 blocks x 256 threads (4 waves). Work item = (head, 128 q-rows); 512
// items total, popped heaviest-first via atomic counter (near-perfect CU
// balance under any block->CU mapping). Wave w owns rows [w*32, w*32+32) of
// the item as two 16-row m-groups sharing K/V fragment reads. One staged
// 64-key tile (K hi/lo + V^T, bf16) serves all 128 rows. Per-wave P buffer
// reused across groups (same-wave DS ordering makes write->read->overwrite
// safe). Register prefetch of the next tile overlaps compute.
// ---------------------------------------------------------------------------
__global__ __launch_bounds__(256) void flash_attn_mfma(
    const ushort_t* __restrict__ qk_hi, const ushort_t* __restrict__ qk_lo,
    const ushort_t* __restrict__ v_t,  ushort_t* __restrict__ res_bf,
    unsigned int* __restrict__ work_ctr)
{
    __shared__ __align__(16) ushort_t KsHi[64][72];
    __shared__ __align__(16) ushort_t KsLo[64][72];
    __shared__ __align__(16) ushort_t Vt[64][72];        // V^T tile [d][key]
    __shared__ __align__(16) ushort_t Pb[4][16][72];     // per-wave, g-reused
    __shared__ unsigned int s_item;

    const int tid  = threadIdx.x;
    const int wave = tid >> 6;
    const int lane = tid & 63;
    const int l16  = lane & 15;
    const int quad = lane >> 4;
    const int srow = tid >> 3;          // 0..31
    const int sc8  = (tid & 7) * 8;     // 0..56

    while (true) {
        __syncthreads();   // everyone done with previous item's LDS + s_item
        if (tid == 0) s_item = atomicAdd(work_ctr, 1u);
        __syncthreads();
        const unsigned int it = s_item;
        if (it >= 512u) break;

        const int h      = (int)(it & 15u);
        const int rb     = 31 - (int)(it >> 4);     // heaviest (rb=31) first
        const int q0     = rb * 128 + wave * 32;    // this wave's first q row
        const int kb_max = rb * 128 + 64;           // last k-tile start

        // ---- Q fragments for both 16-row groups ---------------------------
        short8 qhi[2][2], qlo[2][2];
#pragma unroll
        for (int g = 0; g < 2; ++g) {
            const size_t qoff = (size_t)(q0 + g * 16 + l16) * 2048 + h * HDIM + quad * 8;
            qhi[g][0] = *(const short8*)(qk_hi + qoff);
            qhi[g][1] = *(const short8*)(qk_hi + qoff + 32);
            qlo[g][0] = *(const short8*)(qk_lo + qoff);
            qlo[g][1] = *(const short8*)(qk_lo + qoff + 32);
        }

        float4_t o[2][4];
        float m[2][4], l[2][4];
#pragma unroll
        for (int g = 0; g < 2; ++g)
#pragma unroll
            for (int c = 0; c < 4; ++c) {
                o[g][c] = (float4_t){0.f, 0.f, 0.f, 0.f};
                m[g][c] = -INFINITY; l[g][c] = 0.f;
            }

        // ---- register prefetch of tile kb=0 (2 rows/plane/thread) ---------
        short8 pf_kh[2], pf_kl[2], pf_v[2];
#pragma unroll
        for (int p = 0; p < 2; ++p) {
            const int r = srow + p * 32;
            pf_kh[p] = *(const short8*)(qk_hi + (size_t)r * 2048 + 1024 + h * HDIM + sc8);
            pf_kl[p] = *(const short8*)(qk_lo + (size_t)r * 2048 + 1024 + h * HDIM + sc8);
            pf_v[p]  = *(const short8*)(v_t  + (size_t)(h * HDIM + r) * 4096 + sc8);
        }

        for (int kb = 0; kb <= kb_max; kb += 64) {
            __syncthreads();   // previous iteration's readers done
#pragma unroll
            for (int p = 0; p < 2; ++p) {
                const int r = srow + p * 32;
                *(short8*)&KsHi[r][sc8] = pf_kh[p];
                *(short8*)&KsLo[r][sc8] = pf_kl[p];
                *(short8*)&Vt[r][sc8]   = pf_v[p];
            }
            __syncthreads();   // tile visible to all waves

            if (kb < kb_max) {   // prefetch next tile (overlaps compute)
                const int kn = kb + 64;
#pragma unroll
                for (int p = 0; p < 2; ++p) {
                    const int r = srow + p * 32;
                    pf_kh[p] = *(const short8*)(qk_hi + (size_t)(kn + r) * 2048 + 1024 + h * HDIM + sc8);
                    pf_kl[p] = *(const short8*)(qk_lo + (size_t)(kn + r) * 2048 + 1024 + h * HDIM + sc8);
                    pf_v[p]  = *(const short8*)(v_t  + (size_t)(h * HDIM + r) * 4096 + kn + sc8);
                }
            }

            if (kb > q0 + 31) continue;   // fully-masked tile for this wave

            // ---- S = Q K^T for both groups, shared B-fragment reads -------
            float4_t s[2][4];
#pragma unroll
            for (int t = 0; t < 4; ++t) {
                const int kr = t * 16 + l16;
                short8 bh0 = *(const short8*)&KsHi[kr][quad * 8];
                short8 bh1 = *(const short8*)&KsHi[kr][32 + quad * 8];
                short8 bl0 = *(const short8*)&KsLo[kr][quad * 8];
                short8 bl1 = *(const short8*)&KsLo[kr][32 + quad * 8];
#pragma unroll
                for (int g = 0; g < 2; ++g) {
                    float4_t a = (float4_t){0.f, 0.f, 0.f, 0.f};
                    a = __builtin_amdgcn_mfma_f32_16x16x32_bf16(qhi[g][0], bh0, a, 0, 0, 0);
                    a = __builtin_amdgcn_mfma_f32_16x16x32_bf16(qhi[g][1], bh1, a, 0, 0, 0);
                    a = __builtin_amdgcn_mfma_f32_16x16x32_bf16(qlo[g][0], bh0, a, 0, 0, 0);
                    a = __builtin_amdgcn_mfma_f32_16x16x32_bf16(qlo[g][1], bh1, a, 0, 0, 0);
                    a = __builtin_amdgcn_mfma_f32_16x16x32_bf16(qhi[g][0], bl0, a, 0, 0, 0);
                    a = __builtin_amdgcn_mfma_f32_16x16x32_bf16(qhi[g][1], bl1, a, 0, 0, 0);
                    s[g][t] = a;
                }
            }

            // ---- causal mask (only near-diagonal tiles) -------------------
            if (kb + 63 > q0) {
#pragma unroll
                for (int t = 0; t < 4; ++t) {
                    const int c = kb + t * 16 + l16;
#pragma unroll
                    for (int g = 0; g < 2; ++g)
#pragma unroll
                        for (int r = 0; r < 4; ++r) {
                            const int row = q0 + g * 16 + quad * 4 + r;
                            if (c > row) s[g][t][r] = -INFINITY;
                        }
                }
            }

            // ---- online softmax; P relayout via per-wave LDS, g-reused ----
            short8 pa[2][2];
#pragma unroll
            for (int g = 0; g < 2; ++g) {
#pragma unroll
                for (int r = 0; r < 4; ++r) {
                    float mx = fmaxf(fmaxf(s[g][0][r], s[g][1][r]),
                                     fmaxf(s[g][2][r], s[g][3][r]));
#pragma unroll
                    for (int off = 1; off < 16; off <<= 1)
                        mx = fmaxf(mx, __shfl_xor(mx, off));
                    float mnew  = fmaxf(m[g][r], mx);
                    float alpha = __expf(m[g][r] - mnew);
                    float rowsum = 0.f;
#pragma unroll
                    for (int t = 0; t < 4; ++t) {
                        float p = __expf(s[g][t][r] - mnew);
                        rowsum += p;
                        Pb[wave][quad * 4 + r][t * 16 + l16] = f2bf_rne(p);
                    }
#pragma unroll
                    for (int off = 1; off < 16; off <<= 1)
                        rowsum += __shfl_xor(rowsum, off);
                    l[g][r] = l[g][r] * alpha + rowsum;
                    m[g][r] = mnew;
#pragma unroll
                    for (int ct = 0; ct < 4; ++ct) o[g][ct][r] *= alpha;
                }
                // read this group's P before overwriting (same-wave order)
                pa[g][0] = *(const short8*)&Pb[wave][l16][quad * 8];
                pa[g][1] = *(const short8*)&Pb[wave][l16][32 + quad * 8];
            }

            // ---- O += P V, shared V-fragment reads ------------------------
#pragma unroll
            for (int ct = 0; ct < 4; ++ct) {
                const int dr = ct * 16 + l16;
                short8 vb0 = *(const short8*)&Vt[dr][quad * 8];
                short8 vb1 = *(const short8*)&Vt[dr][32 + quad * 8];
#pragma unroll
                for (int g = 0; g < 2; ++g) {
                    o[g][ct] = __builtin_amdgcn_mfma_f32_16x16x32_bf16(pa[g][0], vb0, o[g][ct], 0, 0, 0);
                    o[g][ct] = __builtin_amdgcn_mfma_f32_16x16x32_bf16(pa[g][1], vb1, o[g][ct], 0, 0, 0);
                }
            }
        } // kb

        // ---- epilogue -----------------------------------------------------
#pragma unroll
        for (int g = 0; g < 2; ++g) {
            float inv[4];
#pragma unroll
            for (int r = 0; r < 4; ++r) inv[r] = 1.0f / l[g][r];
#pragma unroll
            for (int ct = 0; ct < 4; ++ct)
#pragma unroll
                for (int r = 0; r < 4; ++r) {
                    const int row = q0 + g * 16 + quad * 4 + r;
                    res_bf[(size_t)row * EMB + h * HDIM + ct * 16 + l16] =
                        f2bf_rne(o[g][ct][r] * inv[r]);
                }
        }
    } // work loop
}

// ---------------------------------------------------------------------------
// launch
// ---------------------------------------------------------------------------
extern "C" void kernel_launch(void* const* d_in, const int* in_sizes, int n_in,
                              void* d_out, int out_size, void* d_ws, size_t ws_size,
                              hipStream_t stream)
{
    const float* x    = (const float*)d_in[0];
    const float* Wqkv = (const float*)d_in[2];
    const float* bqkv = (const float*)d_in[3];
    const float* Wp   = (const float*)d_in[4];
    const float* bp   = (const float*)d_in[5];
    float* out = (float*)d_out;

    ushort_t* xhi = (ushort_t*)d_ws;                     // [4096,1024]
    ushort_t* xlo = xhi + (size_t)4096 * 1024;           // [4096,1024]
    ushort_t* WTh = xlo + (size_t)4096 * 1024;           // [3072,1024]
    ushort_t* WTl = WTh + (size_t)3072 * 1024;
    ushort_t* qkh = WTl + (size_t)3072 * 1024;           // [4096,2048]
    ushort_t* qkl = qkh + (size_t)4096 * 2048;
    ushort_t* vtg = qkl + (size_t)4096 * 2048;           // V^T [1024,4096]
    unsigned int* ctr = (unsigned int*)(vtg + (size_t)1024 * 4096);
    ushort_t* resb = xhi;   // alias: x splits dead after QKV GEMM
    ushort_t* WpT  = xlo;   // alias

    dim3 blk(256);

    split_x<<<4096, blk, 0, stream>>>(x, xhi, xlo);
    transpose_split<true><<<dim3(3072 / 64, 1024 / 64), blk, 0, stream>>>(
        Wqkv, WTh, WTl, 1024, 3072);
    zero_counter<<<1, 64, 0, stream>>>(ctr);

    gemm_mfma<true, 1><<<dim3(3072 / 128, 4096 / 128), blk, 0, stream>>>(
        xhi, xlo, WTh, WTl, bqkv, nullptr, qkh, qkl, vtg, 4096, 3072, 1024);

    transpose_split<false><<<dim3(1024 / 64, 1024 / 64), blk, 0, stream>>>(
        Wp, WpT, nullptr, 1024, 1024);

    flash_attn_mfma<<<dim3(384), blk, 0, stream>>>(qkh, qkl, vtg, resb, ctr);

    gemm_mfma<false, 0><<<dim3(1024 / 128, 4096 / 128), blk, 0, stream>>>(
        resb, resb, WpT, WpT, bp, out, nullptr, nullptr, nullptr, 4096, 1024, 1024);
}

// Round 6
// 404.113 us; speedup vs baseline: 1.1539x; 1.1539x over previous
//
#include <hip/hip_runtime.h>
#include <hip/hip_bf16.h>
#include <math.h>

#define S_LEN 4096
#define EMB   1024
#define NHEAD 16
#define HDIM  64

typedef __attribute__((ext_vector_type(8))) short short8;
typedef __attribute__((ext_vector_type(4))) short short4_t;
typedef __attribute__((ext_vector_type(8))) _Float16 half8;
typedef __attribute__((ext_vector_type(4))) float float4_t;
typedef unsigned short ushort_t;

#define GLOBAL_AS(p) ((const __attribute__((address_space(1))) void*)(p))
#define LDS_AS(p)    ((__attribute__((address_space(3))) void*)(p))

__device__ __forceinline__ unsigned short f2bf_rne(float f) {
    union { float f; unsigned int u; } v; v.f = f;
    unsigned int u = v.u;
    return (unsigned short)((u + 0x7FFF + ((u >> 16) & 1)) >> 16);
}
__device__ __forceinline__ float bfbits2f(unsigned short b) {
    union { unsigned int u; float f; } v; v.u = ((unsigned int)b) << 16;
    return v.f;
}

// ---------------------------------------------------------------------------
// split fp32 -> bf16 hi/lo planes (QKV GEMM input; fp32-accurate products)
// ---------------------------------------------------------------------------
__global__ __launch_bounds__(256) void split_x(
    const float* __restrict__ in, ushort_t* __restrict__ oh, ushort_t* __restrict__ ol)
{
    const int i = blockIdx.x * 256 + threadIdx.x;
    const float4_t v = ((const float4_t*)in)[i];
    short4_t h, l;
#pragma unroll
    for (int j = 0; j < 4; ++j) {
        unsigned short hb = f2bf_rne(v[j]);
        h[j] = (short)hb;
        l[j] = (short)f2bf_rne(v[j] - bfbits2f(hb));
    }
    ((short4_t*)oh)[i] = h;
    ((short4_t*)ol)[i] = l;
}

// ---------------------------------------------------------------------------
// transpose fp32 [R,C] -> [C,R]: bf16 hi/lo (SPLIT) or fp16 (!SPLIT)
// ---------------------------------------------------------------------------
template<bool SPLIT>
__global__ __launch_bounds__(256) void transpose_split(
    const float* __restrict__ in, ushort_t* __restrict__ oh, ushort_t* __restrict__ ol,
    _Float16* __restrict__ ofh, int R, int C)
{
    __shared__ float t[64][65];
    const int r0 = blockIdx.y * 64, c0 = blockIdx.x * 64;
    for (int i = threadIdx.x; i < 64 * 64; i += 256) {
        int r = i >> 6, c = i & 63;
        t[r][c] = in[(size_t)(r0 + r) * C + c0 + c];
    }
    __syncthreads();
    for (int i = threadIdx.x; i < 64 * 64; i += 256) {
        int c = i >> 6, r = i & 63;
        float f = t[r][c];
        if constexpr (SPLIT) {
            unsigned short hb = f2bf_rne(f);
            oh[(size_t)(c0 + c) * R + r0 + r] = hb;
            ol[(size_t)(c0 + c) * R + r0 + r] = f2bf_rne(f - bfbits2f(hb));
        } else {
            ofh[(size_t)(c0 + c) * R + r0 + r] = (_Float16)f;
        }
    }
}

// ---------------------------------------------------------------------------
// QKV GEMM, bf16 hi/lo split (fp32-accurate), m97 structure.
// A [M,K] bf16 hi+lo; B^T [N,K] bf16 hi+lo. acc = AhBh + AhBl + AlBh.
// Epilogue: cols<2048 -> fp16 qk plane [4096,2048]; cols>=2048 -> fp16 V^T
// [1024,4096].
// ---------------------------------------------------------------------------
__global__ __launch_bounds__(256) void gemm_qkv(
    const ushort_t* __restrict__ Ag, const ushort_t* __restrict__ Alg,
    const ushort_t* __restrict__ Bg, const ushort_t* __restrict__ Blg,
    const float* __restrict__ bias,
    _Float16* __restrict__ qk, _Float16* __restrict__ vt, int K)
{
    constexpr int BK = 32;
    __shared__ ushort_t Ah[128 * BK];
    __shared__ ushort_t Bh[128 * BK];
    __shared__ ushort_t Al[128 * BK];
    __shared__ ushort_t Bl[128 * BK];

    const int tid = threadIdx.x;
    const int wave = tid >> 6, lane = tid & 63;
    const int l16 = lane & 15, quad = lane >> 4;
    const int wr = wave >> 1, wc = wave & 1;
    const int row0 = blockIdx.y * 128, col0 = blockIdx.x * 128;
    const int lrow = lane >> 2, lc8 = (lane & 3) * 8;

    float4_t acc[4][4];
#pragma unroll
    for (int i = 0; i < 4; ++i)
#pragma unroll
        for (int j = 0; j < 4; ++j) acc[i][j] = (float4_t){0.f, 0.f, 0.f, 0.f};

    for (int k0 = 0; k0 < K; k0 += BK) {
        __syncthreads();
#pragma unroll
        for (int i = 0; i < 2; ++i) {
            const int ar = i * 64 + wave * 16;
            __builtin_amdgcn_global_load_lds(
                GLOBAL_AS(Ag + (size_t)(row0 + ar + lrow) * K + k0 + lc8),
                LDS_AS(&Ah[ar * BK]), 16, 0, 0);
            __builtin_amdgcn_global_load_lds(
                GLOBAL_AS(Bg + (size_t)(col0 + ar + lrow) * K + k0 + lc8),
                LDS_AS(&Bh[ar * BK]), 16, 0, 0);
            __builtin_amdgcn_global_load_lds(
                GLOBAL_AS(Alg + (size_t)(row0 + ar + lrow) * K + k0 + lc8),
                LDS_AS(&Al[ar * BK]), 16, 0, 0);
            __builtin_amdgcn_global_load_lds(
                GLOBAL_AS(Blg + (size_t)(col0 + ar + lrow) * K + k0 + lc8),
                LDS_AS(&Bl[ar * BK]), 16, 0, 0);
        }
        __syncthreads();

        short8 af[4], bfr[4], afl[4], bfl[4];
#pragma unroll
        for (int t = 0; t < 4; ++t) {
            af[t]  = *(const short8*)&Ah[(wr * 64 + t * 16 + l16) * BK + quad * 8];
            bfr[t] = *(const short8*)&Bh[(wc * 64 + t * 16 + l16) * BK + quad * 8];
            afl[t] = *(const short8*)&Al[(wr * 64 + t * 16 + l16) * BK + quad * 8];
            bfl[t] = *(const short8*)&Bl[(wc * 64 + t * 16 + l16) * BK + quad * 8];
        }
#pragma unroll
        for (int i = 0; i < 4; ++i)
#pragma unroll
            for (int j = 0; j < 4; ++j) {
                acc[i][j] = __builtin_amdgcn_mfma_f32_16x16x32_bf16(af[i],  bfr[j], acc[i][j], 0, 0, 0);
                acc[i][j] = __builtin_amdgcn_mfma_f32_16x16x32_bf16(af[i],  bfl[j], acc[i][j], 0, 0, 0);
                acc[i][j] = __builtin_amdgcn_mfma_f32_16x16x32_bf16(afl[i], bfr[j], acc[i][j], 0, 0, 0);
            }
    }

#pragma unroll
    for (int i = 0; i < 4; ++i) {
#pragma unroll
        for (int j = 0; j < 4; ++j) {
            const int colb = col0 + wc * 64 + j * 16 + l16;
            const float bv = bias[colb];
#pragma unroll
            for (int r = 0; r < 4; ++r) {
                const int row = row0 + wr * 64 + i * 16 + quad * 4 + r;
                const float val = acc[i][j][r] + bv;
                if (colb < 2048) {
                    qk[(size_t)row * 2048 + colb] = (_Float16)val;
                } else {
                    vt[(size_t)(colb - 2048) * 4096 + row] = (_Float16)val;
                }
            }
        }
    }
}

// ---------------------------------------------------------------------------
// Out-projection GEMM, plain fp16. A [M,K] fp16 (res), B^T [N,K] fp16 (Wp^T).
// C fp32 = acc + bias.
// ---------------------------------------------------------------------------
__global__ __launch_bounds__(256) void gemm_out(
    const _Float16* __restrict__ Ag, const _Float16* __restrict__ Bg,
    const float* __restrict__ bias, float* __restrict__ C, int N, int K)
{
    constexpr int BK = 32;
    __shared__ _Float16 Ah[128 * BK];
    __shared__ _Float16 Bh[128 * BK];

    const int tid = threadIdx.x;
    const int wave = tid >> 6, lane = tid & 63;
    const int l16 = lane & 15, quad = lane >> 4;
    const int wr = wave >> 1, wc = wave & 1;
    const int row0 = blockIdx.y * 128, col0 = blockIdx.x * 128;
    const int lrow = lane >> 2, lc8 = (lane & 3) * 8;

    float4_t acc[4][4];
#pragma unroll
    for (int i = 0; i < 4; ++i)
#pragma unroll
        for (int j = 0; j < 4; ++j) acc[i][j] = (float4_t){0.f, 0.f, 0.f, 0.f};

    for (int k0 = 0; k0 < K; k0 += BK) {
        __syncthreads();
#pragma unroll
        for (int i = 0; i < 2; ++i) {
            const int ar = i * 64 + wave * 16;
            __builtin_amdgcn_global_load_lds(
                GLOBAL_AS(Ag + (size_t)(row0 + ar + lrow) * K + k0 + lc8),
                LDS_AS(&Ah[ar * BK]), 16, 0, 0);
            __builtin_amdgcn_global_load_lds(
                GLOBAL_AS(Bg + (size_t)(col0 + ar + lrow) * K + k0 + lc8),
                LDS_AS(&Bh[ar * BK]), 16, 0, 0);
        }
        __syncthreads();

        half8 af[4], bfr[4];
#pragma unroll
        for (int t = 0; t < 4; ++t) {
            af[t]  = *(const half8*)&Ah[(wr * 64 + t * 16 + l16) * BK + quad * 8];
            bfr[t] = *(const half8*)&Bh[(wc * 64 + t * 16 + l16) * BK + quad * 8];
        }
#pragma unroll
        for (int i = 0; i < 4; ++i)
#pragma unroll
            for (int j = 0; j < 4; ++j)
                acc[i][j] = __builtin_amdgcn_mfma_f32_16x16x32_f16(af[i], bfr[j], acc[i][j], 0, 0, 0);
    }

#pragma unroll
    for (int i = 0; i < 4; ++i) {
#pragma unroll
        for (int j = 0; j < 4; ++j) {
            const int colb = col0 + wc * 64 + j * 16 + l16;
            const float bv = bias[colb];
#pragma unroll
            for (int r = 0; r < 4; ++r) {
                const int row = row0 + wr * 64 + i * 16 + quad * 4 + r;
                C[(size_t)row * N + colb] = acc[i][j][r] + bv;
            }
        }
    }
}

// ---------------------------------------------------------------------------
// MFMA causal flash attention, fp16, round-4 paired-static structure.
// Grid (64, 16): block handles 32-row q-tiles {bx, 127-bx} of head by ->
// uniform 65 k-iterations. Block = 128 threads = 2 waves; wave owns 16 q-rows.
// 1024 blocks = 4/CU resident (LDS 23 KB < 160/6) -> 2 waves/SIMD.
// K tile [64 keys][64 d] and V^T tile [64 d][64 keys] staged in LDS fp16;
// register prefetch of next tile overlaps compute. P relayout via per-wave
// LDS buffer (same-wave DS ordering).
// ---------------------------------------------------------------------------
__global__ __launch_bounds__(128, 2) void flash_attn_f16(
    const _Float16* __restrict__ qk, const _Float16* __restrict__ v_t,
    _Float16* __restrict__ resh)
{
    __shared__ __align__(16) _Float16 Ks[64][72];
    __shared__ __align__(16) _Float16 Vt[64][72];      // [d][key]
    __shared__ __align__(16) _Float16 Pb[2][16][72];   // per-wave P

    const int h    = blockIdx.y;
    const int tid  = threadIdx.x;
    const int wave = tid >> 6;
    const int lane = tid & 63;
    const int l16  = lane & 15;
    const int quad = lane >> 4;
    const int srow = tid >> 3;          // 0..15
    const int sc8  = (tid & 7) * 8;     // 0..56

    for (int half = 0; half < 2; ++half) {
        const int tile = half ? 127 - (int)blockIdx.x : (int)blockIdx.x;
        const int bq0  = tile * 32;
        const int q0   = bq0 + wave * 16;
        const int kb_last = (tile >> 1) * 64;   // last 64-key tile start

        // ---- Q fragments ---------------------------------------------------
        const size_t qoff = (size_t)(q0 + l16) * 2048 + h * HDIM + quad * 8;
        half8 qf0 = *(const half8*)(qk + qoff);
        half8 qf1 = *(const half8*)(qk + qoff + 32);

        float4_t o[4];
        float m[4], l[4];
#pragma unroll
        for (int c = 0; c < 4; ++c) {
            o[c] = (float4_t){0.f, 0.f, 0.f, 0.f};
            m[c] = -INFINITY; l[c] = 0.f;
        }

        // ---- register prefetch of tile kb=0 (4 rows/plane/thread) ---------
        half8 pf_k[4], pf_v[4];
#pragma unroll
        for (int p = 0; p < 4; ++p) {
            const int r = srow + p * 16;
            pf_k[p] = *(const half8*)(qk + (size_t)r * 2048 + 1024 + h * HDIM + sc8);
            pf_v[p] = *(const half8*)(v_t + (size_t)(h * HDIM + r) * 4096 + sc8);
        }

        for (int kb = 0; kb <= kb_last; kb += 64) {
            __syncthreads();   // previous iteration's readers done
#pragma unroll
            for (int p = 0; p < 4; ++p) {
                const int r = srow + p * 16;
                *(half8*)&Ks[r][sc8] = pf_k[p];
                *(half8*)&Vt[r][sc8] = pf_v[p];
            }
            __syncthreads();   // tile visible to all waves

            if (kb < kb_last) {   // prefetch next tile (overlaps compute)
                const int kn = kb + 64;
#pragma unroll
                for (int p = 0; p < 4; ++p) {
                    const int r = srow + p * 16;
                    pf_k[p] = *(const half8*)(qk + (size_t)(kn + r) * 2048 + 1024 + h * HDIM + sc8);
                    pf_v[p] = *(const half8*)(v_t + (size_t)(h * HDIM + r) * 4096 + kn + sc8);
                }
            }

            if (kb > q0 + 15) continue;   // fully-masked tile for this wave

            // ---- S = Q K^T -------------------------------------------------
            float4_t s[4];
#pragma unroll
            for (int t = 0; t < 4; ++t) {
                const int kr = t * 16 + l16;
                half8 b0 = *(const half8*)&Ks[kr][quad * 8];
                half8 b1 = *(const half8*)&Ks[kr][32 + quad * 8];
                float4_t a = (float4_t){0.f, 0.f, 0.f, 0.f};
                a = __builtin_amdgcn_mfma_f32_16x16x32_f16(qf0, b0, a, 0, 0, 0);
                a = __builtin_amdgcn_mfma_f32_16x16x32_f16(qf1, b1, a, 0, 0, 0);
                s[t] = a;
            }

            // ---- causal mask (only the diagonal-straddling tile) ----------
            if (kb + 63 > q0) {
#pragma unroll
                for (int t = 0; t < 4; ++t) {
                    const int c = kb + t * 16 + l16;
#pragma unroll
                    for (int r = 0; r < 4; ++r) {
                        const int row = q0 + quad * 4 + r;
                        if (c > row) s[t][r] = -INFINITY;
                    }
                }
            }

            // ---- online softmax -------------------------------------------
#pragma unroll
            for (int r = 0; r < 4; ++r) {
                float mx = fmaxf(fmaxf(s[0][r], s[1][r]), fmaxf(s[2][r], s[3][r]));
#pragma unroll
                for (int off = 1; off < 16; off <<= 1)
                    mx = fmaxf(mx, __shfl_xor(mx, off));
                float mnew  = fmaxf(m[r], mx);
                float alpha = __expf(m[r] - mnew);
                float rowsum = 0.f;
#pragma unroll
                for (int t = 0; t < 4; ++t) {
                    float p = __expf(s[t][r] - mnew);
                    rowsum += p;
                    Pb[wave][quad * 4 + r][t * 16 + l16] = (_Float16)p;
                }
#pragma unroll
                for (int off = 1; off < 16; off <<= 1)
                    rowsum += __shfl_xor(rowsum, off);
                l[r] = l[r] * alpha + rowsum;
                m[r] = mnew;
#pragma unroll
                for (int ct = 0; ct < 4; ++ct) o[ct][r] *= alpha;
            }

            // ---- O += P V --------------------------------------------------
            half8 pa0 = *(const half8*)&Pb[wave][l16][quad * 8];
            half8 pa1 = *(const half8*)&Pb[wave][l16][32 + quad * 8];
#pragma unroll
            for (int ct = 0; ct < 4; ++ct) {
                const int dr = ct * 16 + l16;
                half8 vb0 = *(const half8*)&Vt[dr][quad * 8];
                half8 vb1 = *(const half8*)&Vt[dr][32 + quad * 8];
                o[ct] = __builtin_amdgcn_mfma_f32_16x16x32_f16(pa0, vb0, o[ct], 0, 0, 0);
                o[ct] = __builtin_amdgcn_mfma_f32_16x16x32_f16(pa1, vb1, o[ct], 0, 0, 0);
            }
        } // kb

        // ---- epilogue ------------------------------------------------------
        float inv[4];
#pragma unroll
        for (int r = 0; r < 4; ++r) inv[r] = 1.0f / l[r];
#pragma unroll
        for (int ct = 0; ct < 4; ++ct)
#pragma unroll
            for (int r = 0; r < 4; ++r) {
                const int row = q0 + quad * 4 + r;
                resh[(size_t)row * EMB + h * HDIM + ct * 16 + l16] =
                    (_Float16)(o[ct][r] * inv[r]);
            }
    } // half
}

// ---------------------------------------------------------------------------
// launch
// ---------------------------------------------------------------------------
extern "C" void kernel_launch(void* const* d_in, const int* in_sizes, int n_in,
                              void* d_out, int out_size, void* d_ws, size_t ws_size,
                              hipStream_t stream)
{
    const float* x    = (const float*)d_in[0];
    const float* Wqkv = (const float*)d_in[2];
    const float* bqkv = (const float*)d_in[3];
    const float* Wp   = (const float*)d_in[4];
    const float* bp   = (const float*)d_in[5];
    float* out = (float*)d_out;

    ushort_t* xhi = (ushort_t*)d_ws;                     // [4096,1024] bf16
    ushort_t* xlo = xhi + (size_t)4096 * 1024;
    ushort_t* WTh = xlo + (size_t)4096 * 1024;           // [3072,1024] bf16
    ushort_t* WTl = WTh + (size_t)3072 * 1024;
    _Float16* qkh = (_Float16*)(WTl + (size_t)3072 * 1024);  // [4096,2048] fp16
    _Float16* vtg = qkh + (size_t)4096 * 2048;           // V^T [1024,4096] fp16
    _Float16* resh = (_Float16*)xhi;   // alias: x splits dead after QKV GEMM
    _Float16* WpT  = (_Float16*)xlo;   // alias

    dim3 blk(256);

    split_x<<<4096, blk, 0, stream>>>(x, xhi, xlo);
    transpose_split<true><<<dim3(3072 / 64, 1024 / 64), blk, 0, stream>>>(
        Wqkv, WTh, WTl, nullptr, 1024, 3072);

    gemm_qkv<<<dim3(3072 / 128, 4096 / 128), blk, 0, stream>>>(
        xhi, xlo, WTh, WTl, bqkv, qkh, vtg, 1024);

    transpose_split<false><<<dim3(1024 / 64, 1024 / 64), blk, 0, stream>>>(
        Wp, nullptr, nullptr, WpT, 1024, 1024);

    flash_attn_f16<<<dim3(64, NHEAD), dim3(128), 0, stream>>>(qkh, vtg, resh);

    gemm_out<<<dim3(1024 / 128, 4096 / 128), blk, 0, stream>>>(
        resh, WpT, bp, out, 1024, 1024);
}

// Round 7
// 338.400 us; speedup vs baseline: 1.3780x; 1.1942x over previous
//
#include <hip/hip_runtime.h>
#include <hip/hip_bf16.h>
#include <math.h>

#define S_LEN 4096
#define EMB   1024
#define NHEAD 16
#define HDIM  64

typedef __attribute__((ext_vector_type(8))) _Float16 half8;
typedef __attribute__((ext_vector_type(4))) _Float16 half4;
typedef __attribute__((ext_vector_type(4))) float float4_t;

#define GLOBAL_AS(p) ((const __attribute__((address_space(1))) void*)(p))
#define LDS_AS(p)    ((__attribute__((address_space(3))) void*)(p))

#define LOG2E 1.4426950408889634f

// ---------------------------------------------------------------------------
// convert fp32 -> fp16, row-major (x for QKV GEMM A operand)
// ---------------------------------------------------------------------------
__global__ __launch_bounds__(256) void convert_f16(
    const float* __restrict__ in, _Float16* __restrict__ out)
{
    const int i = blockIdx.x * 256 + threadIdx.x;
    const float4_t v = ((const float4_t*)in)[i];
    half4 h;
#pragma unroll
    for (int j = 0; j < 4; ++j) h[j] = (_Float16)v[j];
    ((half4*)out)[i] = h;
}

// ---------------------------------------------------------------------------
// transpose fp32 [R,C] -> fp16 [C,R]  (weights -> B^T layout)
// ---------------------------------------------------------------------------
__global__ __launch_bounds__(256) void transpose_f16(
    const float* __restrict__ in, _Float16* __restrict__ out, int R, int C)
{
    __shared__ float t[64][65];
    const int r0 = blockIdx.y * 64, c0 = blockIdx.x * 64;
    for (int i = threadIdx.x; i < 64 * 64; i += 256) {
        int r = i >> 6, c = i & 63;
        t[r][c] = in[(size_t)(r0 + r) * C + c0 + c];
    }
    __syncthreads();
    for (int i = threadIdx.x; i < 64 * 64; i += 256) {
        int c = i >> 6, r = i & 63;
        out[(size_t)(c0 + c) * R + r0 + r] = (_Float16)t[r][c];
    }
}

// ---------------------------------------------------------------------------
// QKV GEMM, plain fp16, m97 structure: 128x128 tile, BK=32, global_load_lds.
// A [4096,1024] fp16 (x); B^T [3072,1024] fp16 (Wqkv^T). acc fp32.
// Epilogue: cols<1024 -> q plane; 1024..2047 -> k plane SCALED by log2(e)
// (so attention can use raw v_exp_f32 = exp2); cols>=2048 -> fp16 V^T
// [1024,4096].
// ---------------------------------------------------------------------------
__global__ __launch_bounds__(256) void gemm_qkv(
    const _Float16* __restrict__ Ag, const _Float16* __restrict__ Bg,
    const float* __restrict__ bias,
    _Float16* __restrict__ qk, _Float16* __restrict__ vt, int K)
{
    constexpr int BK = 32;
    __shared__ _Float16 Ah[128 * BK];
    __shared__ _Float16 Bh[128 * BK];

    const int tid = threadIdx.x;
    const int wave = tid >> 6, lane = tid & 63;
    const int l16 = lane & 15, quad = lane >> 4;
    const int wr = wave >> 1, wc = wave & 1;
    const int row0 = blockIdx.y * 128, col0 = blockIdx.x * 128;
    const int lrow = lane >> 2, lc8 = (lane & 3) * 8;

    float4_t acc[4][4];
#pragma unroll
    for (int i = 0; i < 4; ++i)
#pragma unroll
        for (int j = 0; j < 4; ++j) acc[i][j] = (float4_t){0.f, 0.f, 0.f, 0.f};

    for (int k0 = 0; k0 < K; k0 += BK) {
        __syncthreads();
#pragma unroll
        for (int i = 0; i < 2; ++i) {
            const int ar = i * 64 + wave * 16;
            __builtin_amdgcn_global_load_lds(
                GLOBAL_AS(Ag + (size_t)(row0 + ar + lrow) * K + k0 + lc8),
                LDS_AS(&Ah[ar * BK]), 16, 0, 0);
            __builtin_amdgcn_global_load_lds(
                GLOBAL_AS(Bg + (size_t)(col0 + ar + lrow) * K + k0 + lc8),
                LDS_AS(&Bh[ar * BK]), 16, 0, 0);
        }
        __syncthreads();

        half8 af[4], bfr[4];
#pragma unroll
        for (int t = 0; t < 4; ++t) {
            af[t]  = *(const half8*)&Ah[(wr * 64 + t * 16 + l16) * BK + quad * 8];
            bfr[t] = *(const half8*)&Bh[(wc * 64 + t * 16 + l16) * BK + quad * 8];
        }
#pragma unroll
        for (int i = 0; i < 4; ++i)
#pragma unroll
            for (int j = 0; j < 4; ++j)
                acc[i][j] = __builtin_amdgcn_mfma_f32_16x16x32_f16(af[i], bfr[j], acc[i][j], 0, 0, 0);
    }

#pragma unroll
    for (int i = 0; i < 4; ++i) {
#pragma unroll
        for (int j = 0; j < 4; ++j) {
            const int colb = col0 + wc * 64 + j * 16 + l16;
            const float bv = bias[colb];
#pragma unroll
            for (int r = 0; r < 4; ++r) {
                const int row = row0 + wr * 64 + i * 16 + quad * 4 + r;
                float val = acc[i][j][r] + bv;
                if (colb < 2048) {
                    if (colb >= 1024) val *= LOG2E;   // k plane pre-scaled
                    qk[(size_t)row * 2048 + colb] = (_Float16)val;
                } else {
                    vt[(size_t)(colb - 2048) * 4096 + row] = (_Float16)val;
                }
            }
        }
    }
}

// ---------------------------------------------------------------------------
// Out-projection GEMM, plain fp16. A [M,K] fp16 (res), B^T [N,K] fp16 (Wp^T).
// ---------------------------------------------------------------------------
__global__ __launch_bounds__(256) void gemm_out(
    const _Float16* __restrict__ Ag, const _Float16* __restrict__ Bg,
    const float* __restrict__ bias, float* __restrict__ C, int N, int K)
{
    constexpr int BK = 32;
    __shared__ _Float16 Ah[128 * BK];
    __shared__ _Float16 Bh[128 * BK];

    const int tid = threadIdx.x;
    const int wave = tid >> 6, lane = tid & 63;
    const int l16 = lane & 15, quad = lane >> 4;
    const int wr = wave >> 1, wc = wave & 1;
    const int row0 = blockIdx.y * 128, col0 = blockIdx.x * 128;
    const int lrow = lane >> 2, lc8 = (lane & 3) * 8;

    float4_t acc[4][4];
#pragma unroll
    for (int i = 0; i < 4; ++i)
#pragma unroll
        for (int j = 0; j < 4; ++j) acc[i][j] = (float4_t){0.f, 0.f, 0.f, 0.f};

    for (int k0 = 0; k0 < K; k0 += BK) {
        __syncthreads();
#pragma unroll
        for (int i = 0; i < 2; ++i) {
            const int ar = i * 64 + wave * 16;
            __builtin_amdgcn_global_load_lds(
                GLOBAL_AS(Ag + (size_t)(row0 + ar + lrow) * K + k0 + lc8),
                LDS_AS(&Ah[ar * BK]), 16, 0, 0);
            __builtin_amdgcn_global_load_lds(
                GLOBAL_AS(Bg + (size_t)(col0 + ar + lrow) * K + k0 + lc8),
                LDS_AS(&Bh[ar * BK]), 16, 0, 0);
        }
        __syncthreads();

        half8 af[4], bfr[4];
#pragma unroll
        for (int t = 0; t < 4; ++t) {
            af[t]  = *(const half8*)&Ah[(wr * 64 + t * 16 + l16) * BK + quad * 8];
            bfr[t] = *(const half8*)&Bh[(wc * 64 + t * 16 + l16) * BK + quad * 8];
        }
#pragma unroll
        for (int i = 0; i < 4; ++i)
#pragma unroll
            for (int j = 0; j < 4; ++j)
                acc[i][j] = __builtin_amdgcn_mfma_f32_16x16x32_f16(af[i], bfr[j], acc[i][j], 0, 0, 0);
    }

#pragma unroll
    for (int i = 0; i < 4; ++i) {
#pragma unroll
        for (int j = 0; j < 4; ++j) {
            const int colb = col0 + wc * 64 + j * 16 + l16;
            const float bv = bias[colb];
#pragma unroll
            for (int r = 0; r < 4; ++r) {
                const int row = row0 + wr * 64 + i * 16 + quad * 4 + r;
                C[(size_t)row * N + colb] = acc[i][j][r] + bv;
            }
        }
    }
}

// ---------------------------------------------------------------------------
// MFMA causal flash attention, fp16, XCD-aware paired-static structure.
// 1D grid of 1024 blocks x 128 threads (2 waves). Block bid:
//   xcd  = bid & 7          (workgroups dispatch round-robin over 8 XCDs)
//   head = xcd*2 + ((bid>>3)&1)   -> each XCD touches only 2 heads
//                                    (2 MB K/V working set <= 4 MB XCD L2)
//   pair = bid >> 4 (0..63) -> tiles {pair, 127-pair}: uniform 65 k-iters.
// Wave owns 16 q-rows. K plane is pre-scaled by log2(e) -> exp via raw
// v_exp_f32 (exp2). Pb stride 76 halves: quad bank bases {0,24,16,8} mod 32
// -> conflict-free scalar writes; reads via 8B-aligned half4 pairs.
// ---------------------------------------------------------------------------
__global__ __launch_bounds__(128, 2) void flash_attn_f16(
    const _Float16* __restrict__ qk, const _Float16* __restrict__ v_t,
    _Float16* __restrict__ resh)
{
    __shared__ __align__(16) _Float16 Ks[64][72];
    __shared__ __align__(16) _Float16 Vt[64][72];      // [d][key]
    __shared__ __align__(16) _Float16 Pb[2][16][76];   // per-wave P, stride 76

    const int bid  = blockIdx.x;
    const int h    = (bid & 7) * 2 + ((bid >> 3) & 1);
    const int pair = bid >> 4;          // 0..63
    const int tid  = threadIdx.x;
    const int wave = tid >> 6;
    const int lane = tid & 63;
    const int l16  = lane & 15;
    const int quad = lane >> 4;
    const int srow = tid >> 3;          // 0..15
    const int sc8  = (tid & 7) * 8;     // 0..56

    for (int half = 0; half < 2; ++half) {
        const int tile = half ? 127 - pair : pair;
        const int q0   = tile * 32 + wave * 16;
        const int kb_last = (tile >> 1) * 64;   // last 64-key tile start

        // ---- Q fragments ---------------------------------------------------
        const size_t qoff = (size_t)(q0 + l16) * 2048 + h * HDIM + quad * 8;
        half8 qf0 = *(const half8*)(qk + qoff);
        half8 qf1 = *(const half8*)(qk + qoff + 32);

        float4_t o[4];
        float m[4], l[4];
#pragma unroll
        for (int c = 0; c < 4; ++c) {
            o[c] = (float4_t){0.f, 0.f, 0.f, 0.f};
            m[c] = -INFINITY; l[c] = 0.f;
        }

        // ---- register prefetch of tile kb=0 -------------------------------
        half8 pf_k[4], pf_v[4];
#pragma unroll
        for (int p = 0; p < 4; ++p) {
            const int r = srow + p * 16;
            pf_k[p] = *(const half8*)(qk + (size_t)r * 2048 + 1024 + h * HDIM + sc8);
            pf_v[p] = *(const half8*)(v_t + (size_t)(h * HDIM + r) * 4096 + sc8);
        }

        for (int kb = 0; kb <= kb_last; kb += 64) {
            __syncthreads();   // previous iteration's readers done
#pragma unroll
            for (int p = 0; p < 4; ++p) {
                const int r = srow + p * 16;
                *(half8*)&Ks[r][sc8] = pf_k[p];
                *(half8*)&Vt[r][sc8] = pf_v[p];
            }
            __syncthreads();   // tile visible to all waves

            if (kb < kb_last) {   // prefetch next tile (overlaps compute)
                const int kn = kb + 64;
#pragma unroll
                for (int p = 0; p < 4; ++p) {
                    const int r = srow + p * 16;
                    pf_k[p] = *(const half8*)(qk + (size_t)(kn + r) * 2048 + 1024 + h * HDIM + sc8);
                    pf_v[p] = *(const half8*)(v_t + (size_t)(h * HDIM + r) * 4096 + kn + sc8);
                }
            }

            if (kb > q0 + 15) continue;   // fully-masked tile for this wave

            // ---- S = Q K^T (log2-domain logits) ---------------------------
            float4_t s[4];
#pragma unroll
            for (int t = 0; t < 4; ++t) {
                const int kr = t * 16 + l16;
                half8 b0 = *(const half8*)&Ks[kr][quad * 8];
                half8 b1 = *(const half8*)&Ks[kr][32 + quad * 8];
                float4_t a = (float4_t){0.f, 0.f, 0.f, 0.f};
                a = __builtin_amdgcn_mfma_f32_16x16x32_f16(qf0, b0, a, 0, 0, 0);
                a = __builtin_amdgcn_mfma_f32_16x16x32_f16(qf1, b1, a, 0, 0, 0);
                s[t] = a;
            }

            // ---- causal mask (only the diagonal-straddling tile) ----------
            if (kb + 63 > q0) {
#pragma unroll
                for (int t = 0; t < 4; ++t) {
                    const int c = kb + t * 16 + l16;
#pragma unroll
                    for (int r = 0; r < 4; ++r) {
                        const int row = q0 + quad * 4 + r;
                        if (c > row) s[t][r] = -INFINITY;
                    }
                }
            }

            // ---- online softmax (base-2 domain) ---------------------------
#pragma unroll
            for (int r = 0; r < 4; ++r) {
                float mx = fmaxf(fmaxf(s[0][r], s[1][r]), fmaxf(s[2][r], s[3][r]));
#pragma unroll
                for (int off = 1; off < 16; off <<= 1)
                    mx = fmaxf(mx, __shfl_xor(mx, off));
                float mnew  = fmaxf(m[r], mx);
                float alpha = __builtin_amdgcn_exp2f(m[r] - mnew);
                float rowsum = 0.f;
#pragma unroll
                for (int t = 0; t < 4; ++t) {
                    float p = __builtin_amdgcn_exp2f(s[t][r] - mnew);
                    rowsum += p;
                    Pb[wave][quad * 4 + r][t * 16 + l16] = (_Float16)p;
                }
#pragma unroll
                for (int off = 1; off < 16; off <<= 1)
                    rowsum += __shfl_xor(rowsum, off);
                l[r] = l[r] * alpha + rowsum;
                m[r] = mnew;
#pragma unroll
                for (int ct = 0; ct < 4; ++ct) o[ct][r] *= alpha;
            }

            // ---- O += P V (Pb reads: two 8B-aligned half4 each) -----------
            half4 p00 = *(const half4*)&Pb[wave][l16][quad * 8];
            half4 p01 = *(const half4*)&Pb[wave][l16][quad * 8 + 4];
            half4 p10 = *(const half4*)&Pb[wave][l16][32 + quad * 8];
            half4 p11 = *(const half4*)&Pb[wave][l16][32 + quad * 8 + 4];
            half8 pa0, pa1;
#pragma unroll
            for (int j = 0; j < 4; ++j) {
                pa0[j] = p00[j]; pa0[4 + j] = p01[j];
                pa1[j] = p10[j]; pa1[4 + j] = p11[j];
            }
#pragma unroll
            for (int ct = 0; ct < 4; ++ct) {
                const int dr = ct * 16 + l16;
                half8 vb0 = *(const half8*)&Vt[dr][quad * 8];
                half8 vb1 = *(const half8*)&Vt[dr][32 + quad * 8];
                o[ct] = __builtin_amdgcn_mfma_f32_16x16x32_f16(pa0, vb0, o[ct], 0, 0, 0);
                o[ct] = __builtin_amdgcn_mfma_f32_16x16x32_f16(pa1, vb1, o[ct], 0, 0, 0);
            }
        } // kb

        // ---- epilogue ------------------------------------------------------
        float inv[4];
#pragma unroll
        for (int r = 0; r < 4; ++r) inv[r] = 1.0f / l[r];
#pragma unroll
        for (int ct = 0; ct < 4; ++ct)
#pragma unroll
            for (int r = 0; r < 4; ++r) {
                const int row = q0 + quad * 4 + r;
                resh[(size_t)row * EMB + h * HDIM + ct * 16 + l16] =
                    (_Float16)(o[ct][r] * inv[r]);
            }
    } // half
}

// ---------------------------------------------------------------------------
// launch
// ---------------------------------------------------------------------------
extern "C" void kernel_launch(void* const* d_in, const int* in_sizes, int n_in,
                              void* d_out, int out_size, void* d_ws, size_t ws_size,
                              hipStream_t stream)
{
    const float* x    = (const float*)d_in[0];
    const float* Wqkv = (const float*)d_in[2];
    const float* bqkv = (const float*)d_in[3];
    const float* Wp   = (const float*)d_in[4];
    const float* bp   = (const float*)d_in[5];
    float* out = (float*)d_out;

    _Float16* xh  = (_Float16*)d_ws;                 // [4096,1024] fp16
    _Float16* WTh = xh + (size_t)4096 * 1024;        // [3072,1024] fp16
    _Float16* qkh = WTh + (size_t)3072 * 1024;       // [4096,2048] fp16
    _Float16* vtg = qkh + (size_t)4096 * 2048;       // V^T [1024,4096] fp16
    _Float16* resh = xh;            // alias: x fp16 dead after QKV GEMM
    _Float16* WpT  = WTh;           // alias: Wqkv^T dead after QKV GEMM

    dim3 blk(256);

    convert_f16<<<4096, blk, 0, stream>>>(x, xh);
    transpose_f16<<<dim3(3072 / 64, 1024 / 64), blk, 0, stream>>>(
        Wqkv, WTh, 1024, 3072);

    gemm_qkv<<<dim3(3072 / 128, 4096 / 128), blk, 0, stream>>>(
        xh, WTh, bqkv, qkh, vtg, 1024);

    transpose_f16<<<dim3(1024 / 64, 1024 / 64), blk, 0, stream>>>(
        Wp, WpT, 1024, 1024);

    flash_attn_f16<<<dim3(1024), dim3(128), 0, stream>>>(qkh, vtg, resh);

    gemm_out<<<dim3(1024 / 128, 4096 / 128), blk, 0, stream>>>(
        resh, WpT, bp, out, 1024, 1024);
}

// Round 8
// 287.008 us; speedup vs baseline: 1.6247x; 1.1791x over previous
//
#include <hip/hip_runtime.h>
#include <hip/hip_bf16.h>
#include <math.h>

#define S_LEN 4096
#define EMB   1024
#define NHEAD 16
#define HDIM  64

typedef __attribute__((ext_vector_type(8))) _Float16 half8;
typedef __attribute__((ext_vector_type(4))) _Float16 half4;
typedef __attribute__((ext_vector_type(4))) float float4_t;

#define GLOBAL_AS(p) ((const __attribute__((address_space(1))) void*)(p))
#define LDS_AS(p)    ((__attribute__((address_space(3))) void*)(p))

#define LOG2E 1.4426950408889634f

// ---------------------------------------------------------------------------
// convert fp32 -> fp16, row-major (x for QKV GEMM A operand)
// ---------------------------------------------------------------------------
__global__ __launch_bounds__(256) void convert_f16(
    const float* __restrict__ in, _Float16* __restrict__ out)
{
    const int i = blockIdx.x * 256 + threadIdx.x;
    const float4_t v = ((const float4_t*)in)[i];
    half4 h;
#pragma unroll
    for (int j = 0; j < 4; ++j) h[j] = (_Float16)v[j];
    ((half4*)out)[i] = h;
}

// ---------------------------------------------------------------------------
// transpose fp32 [R,C] -> fp16 [C,R]  (weights -> B^T layout)
// ---------------------------------------------------------------------------
__global__ __launch_bounds__(256) void transpose_f16(
    const float* __restrict__ in, _Float16* __restrict__ out, int R, int C)
{
    __shared__ float t[64][65];
    const int r0 = blockIdx.y * 64, c0 = blockIdx.x * 64;
    for (int i = threadIdx.x; i < 64 * 64; i += 256) {
        int r = i >> 6, c = i & 63;
        t[r][c] = in[(size_t)(r0 + r) * C + c0 + c];
    }
    __syncthreads();
    for (int i = threadIdx.x; i < 64 * 64; i += 256) {
        int c = i >> 6, r = i & 63;
        out[(size_t)(c0 + c) * R + r0 + r] = (_Float16)t[r][c];
    }
}

// ---------------------------------------------------------------------------
// QKV GEMM, plain fp16, m97 structure: 128x128 tile, BK=32, global_load_lds.
// Epilogue: cols<1024 -> q plane; 1024..2047 -> k plane SCALED by log2(e);
// cols>=2048 -> fp16 V^T [1024,4096].
// ---------------------------------------------------------------------------
__global__ __launch_bounds__(256) void gemm_qkv(
    const _Float16* __restrict__ Ag, const _Float16* __restrict__ Bg,
    const float* __restrict__ bias,
    _Float16* __restrict__ qk, _Float16* __restrict__ vt, int K)
{
    constexpr int BK = 32;
    __shared__ _Float16 Ah[128 * BK];
    __shared__ _Float16 Bh[128 * BK];

    const int tid = threadIdx.x;
    const int wave = tid >> 6, lane = tid & 63;
    const int l16 = lane & 15, quad = lane >> 4;
    const int wr = wave >> 1, wc = wave & 1;
    const int row0 = blockIdx.y * 128, col0 = blockIdx.x * 128;
    const int lrow = lane >> 2, lc8 = (lane & 3) * 8;

    float4_t acc[4][4];
#pragma unroll
    for (int i = 0; i < 4; ++i)
#pragma unroll
        for (int j = 0; j < 4; ++j) acc[i][j] = (float4_t){0.f, 0.f, 0.f, 0.f};

    for (int k0 = 0; k0 < K; k0 += BK) {
        __syncthreads();
#pragma unroll
        for (int i = 0; i < 2; ++i) {
            const int ar = i * 64 + wave * 16;
            __builtin_amdgcn_global_load_lds(
                GLOBAL_AS(Ag + (size_t)(row0 + ar + lrow) * K + k0 + lc8),
                LDS_AS(&Ah[ar * BK]), 16, 0, 0);
            __builtin_amdgcn_global_load_lds(
                GLOBAL_AS(Bg + (size_t)(col0 + ar + lrow) * K + k0 + lc8),
                LDS_AS(&Bh[ar * BK]), 16, 0, 0);
        }
        __syncthreads();

        half8 af[4], bfr[4];
#pragma unroll
        for (int t = 0; t < 4; ++t) {
            af[t]  = *(const half8*)&Ah[(wr * 64 + t * 16 + l16) * BK + quad * 8];
            bfr[t] = *(const half8*)&Bh[(wc * 64 + t * 16 + l16) * BK + quad * 8];
        }
#pragma unroll
        for (int i = 0; i < 4; ++i)
#pragma unroll
            for (int j = 0; j < 4; ++j)
                acc[i][j] = __builtin_amdgcn_mfma_f32_16x16x32_f16(af[i], bfr[j], acc[i][j], 0, 0, 0);
    }

#pragma unroll
    for (int i = 0; i < 4; ++i) {
#pragma unroll
        for (int j = 0; j < 4; ++j) {
            const int colb = col0 + wc * 64 + j * 16 + l16;
            const float bv = bias[colb];
#pragma unroll
            for (int r = 0; r < 4; ++r) {
                const int row = row0 + wr * 64 + i * 16 + quad * 4 + r;
                float val = acc[i][j][r] + bv;
                if (colb < 2048) {
                    if (colb >= 1024) val *= LOG2E;   // k plane pre-scaled
                    qk[(size_t)row * 2048 + colb] = (_Float16)val;
                } else {
                    vt[(size_t)(colb - 2048) * 4096 + row] = (_Float16)val;
                }
            }
        }
    }
}

// ---------------------------------------------------------------------------
// Out-projection GEMM, plain fp16. A [M,K] fp16 (res), B^T [N,K] fp16 (Wp^T).
// ---------------------------------------------------------------------------
__global__ __launch_bounds__(256) void gemm_out(
    const _Float16* __restrict__ Ag, const _Float16* __restrict__ Bg,
    const float* __restrict__ bias, float* __restrict__ C, int N, int K)
{
    constexpr int BK = 32;
    __shared__ _Float16 Ah[128 * BK];
    __shared__ _Float16 Bh[128 * BK];

    const int tid = threadIdx.x;
    const int wave = tid >> 6, lane = tid & 63;
    const int l16 = lane & 15, quad = lane >> 4;
    const int wr = wave >> 1, wc = wave & 1;
    const int row0 = blockIdx.y * 128, col0 = blockIdx.x * 128;
    const int lrow = lane >> 2, lc8 = (lane & 3) * 8;

    float4_t acc[4][4];
#pragma unroll
    for (int i = 0; i < 4; ++i)
#pragma unroll
        for (int j = 0; j < 4; ++j) acc[i][j] = (float4_t){0.f, 0.f, 0.f, 0.f};

    for (int k0 = 0; k0 < K; k0 += BK) {
        __syncthreads();
#pragma unroll
        for (int i = 0; i < 2; ++i) {
            const int ar = i * 64 + wave * 16;
            __builtin_amdgcn_global_load_lds(
                GLOBAL_AS(Ag + (size_t)(row0 + ar + lrow) * K + k0 + lc8),
                LDS_AS(&Ah[ar * BK]), 16, 0, 0);
            __builtin_amdgcn_global_load_lds(
                GLOBAL_AS(Bg + (size_t)(col0 + ar + lrow) * K + k0 + lc8),
                LDS_AS(&Bh[ar * BK]), 16, 0, 0);
        }
        __syncthreads();

        half8 af[4], bfr[4];
#pragma unroll
        for (int t = 0; t < 4; ++t) {
            af[t]  = *(const half8*)&Ah[(wr * 64 + t * 16 + l16) * BK + quad * 8];
            bfr[t] = *(const half8*)&Bh[(wc * 64 + t * 16 + l16) * BK + quad * 8];
        }
#pragma unroll
        for (int i = 0; i < 4; ++i)
#pragma unroll
            for (int j = 0; j < 4; ++j)
                acc[i][j] = __builtin_amdgcn_mfma_f32_16x16x32_f16(af[i], bfr[j], acc[i][j], 0, 0, 0);
    }

#pragma unroll
    for (int i = 0; i < 4; ++i) {
#pragma unroll
        for (int j = 0; j < 4; ++j) {
            const int colb = col0 + wc * 64 + j * 16 + l16;
            const float bv = bias[colb];
#pragma unroll
            for (int r = 0; r < 4; ++r) {
                const int row = row0 + wr * 64 + i * 16 + quad * 4 + r;
                C[(size_t)row * N + colb] = acc[i][j][r] + bv;
            }
        }
    }
}

// ---------------------------------------------------------------------------
// MFMA causal flash attention — S^T formulation.
// S^T = K Q^T (A = K rows from LDS, B = Q frag; B-layout data identical to
// the old A-layout Q, so the same global loads serve). In S^T C-layout
// (row = key = quad*4+r, col = q = l16) every score a lane holds belongs to
// ONE q-row -> row max/sum are per-lane local + 2 cross-quad shuffles; m, l,
// alpha scalars. P store: lane owns 4 consecutive keys per 16-key tile ->
// 4x ds_write_b64 into Pb[q][key]; PV B-operand (B[k=key][n=q]) reads back
// as 2x ds_read_b128 from row q. PV computes O^T = V^T P^T with A = Vt rows.
// Per-wave-iter DS ops: ~34 (was ~76 in the S formulation).
// Grid/XCD mapping, pairing, exp2 domain, prefetch unchanged from round 7.
// ---------------------------------------------------------------------------
__global__ __launch_bounds__(128, 2) void flash_attn_f16(
    const _Float16* __restrict__ qk, const _Float16* __restrict__ v_t,
    _Float16* __restrict__ resh)
{
    __shared__ __align__(16) _Float16 Ks[64][72];
    __shared__ __align__(16) _Float16 Vt[64][72];      // [d][key]
    __shared__ __align__(16) _Float16 Pb[2][16][72];   // per-wave P [q][key]

    const int bid  = blockIdx.x;
    const int h    = (bid & 7) * 2 + ((bid >> 3) & 1);
    const int pair = bid >> 4;          // 0..63
    const int tid  = threadIdx.x;
    const int wave = tid >> 6;
    const int lane = tid & 63;
    const int l16  = lane & 15;
    const int quad = lane >> 4;
    const int srow = tid >> 3;          // 0..15
    const int sc8  = (tid & 7) * 8;     // 0..56

    for (int half = 0; half < 2; ++half) {
        const int tile = half ? 127 - pair : pair;
        const int q0   = tile * 32 + wave * 16;
        const int kb_last = (tile >> 1) * 64;   // last 64-key tile start

        // ---- Q fragment (B-operand: B[k=d][n=q], same data as old A) ------
        const size_t qoff = (size_t)(q0 + l16) * 2048 + h * HDIM + quad * 8;
        half8 qf0 = *(const half8*)(qk + qoff);
        half8 qf1 = *(const half8*)(qk + qoff + 32);

        float4_t o[4];
#pragma unroll
        for (int c = 0; c < 4; ++c) o[c] = (float4_t){0.f, 0.f, 0.f, 0.f};
        float m_r = -INFINITY, l_r = 0.f;

        // ---- register prefetch of tile kb=0 -------------------------------
        half8 pf_k[4], pf_v[4];
#pragma unroll
        for (int p = 0; p < 4; ++p) {
            const int r = srow + p * 16;
            pf_k[p] = *(const half8*)(qk + (size_t)r * 2048 + 1024 + h * HDIM + sc8);
            pf_v[p] = *(const half8*)(v_t + (size_t)(h * HDIM + r) * 4096 + sc8);
        }

        for (int kb = 0; kb <= kb_last; kb += 64) {
            __syncthreads();   // previous iteration's readers done
#pragma unroll
            for (int p = 0; p < 4; ++p) {
                const int r = srow + p * 16;
                *(half8*)&Ks[r][sc8] = pf_k[p];
                *(half8*)&Vt[r][sc8] = pf_v[p];
            }
            __syncthreads();   // tile visible to all waves

            if (kb < kb_last) {   // prefetch next tile (overlaps compute)
                const int kn = kb + 64;
#pragma unroll
                for (int p = 0; p < 4; ++p) {
                    const int r = srow + p * 16;
                    pf_k[p] = *(const half8*)(qk + (size_t)(kn + r) * 2048 + 1024 + h * HDIM + sc8);
                    pf_v[p] = *(const half8*)(v_t + (size_t)(h * HDIM + r) * 4096 + kn + sc8);
                }
            }

            if (kb > q0 + 15) continue;   // fully-masked tile for this wave

            // ---- S^T = K Q^T (log2-domain logits) -------------------------
            float4_t s[4];
#pragma unroll
            for (int t = 0; t < 4; ++t) {
                half8 a0 = *(const half8*)&Ks[t * 16 + l16][quad * 8];
                half8 a1 = *(const half8*)&Ks[t * 16 + l16][32 + quad * 8];
                float4_t a = (float4_t){0.f, 0.f, 0.f, 0.f};
                a = __builtin_amdgcn_mfma_f32_16x16x32_f16(a0, qf0, a, 0, 0, 0);
                a = __builtin_amdgcn_mfma_f32_16x16x32_f16(a1, qf1, a, 0, 0, 0);
                s[t] = a;
            }

            // ---- causal mask: key > q -> -inf (diagonal tiles only) -------
            if (kb + 63 > q0) {
                const int qg = q0 + l16;
#pragma unroll
                for (int t = 0; t < 4; ++t)
#pragma unroll
                    for (int r = 0; r < 4; ++r) {
                        const int key = kb + t * 16 + quad * 4 + r;
                        if (key > qg) s[t][r] = -INFINITY;
                    }
            }

            // ---- online softmax: per-lane local + 2 cross-quad shuffles ---
            float mx = s[0][0];
#pragma unroll
            for (int t = 0; t < 4; ++t)
#pragma unroll
                for (int r = 0; r < 4; ++r) mx = fmaxf(mx, s[t][r]);
            mx = fmaxf(mx, __shfl_xor(mx, 16));
            mx = fmaxf(mx, __shfl_xor(mx, 32));
            const float mnew  = fmaxf(m_r, mx);
            const float alpha = __builtin_amdgcn_exp2f(m_r - mnew);

            float p[4][4];
            float sum = 0.f;
#pragma unroll
            for (int t = 0; t < 4; ++t)
#pragma unroll
                for (int r = 0; r < 4; ++r) {
                    p[t][r] = __builtin_amdgcn_exp2f(s[t][r] - mnew);
                    sum += p[t][r];
                }
            sum += __shfl_xor(sum, 16);
            sum += __shfl_xor(sum, 32);
            l_r = l_r * alpha + sum;
            m_r = mnew;
#pragma unroll
            for (int ct = 0; ct < 4; ++ct)
#pragma unroll
                for (int r = 0; r < 4; ++r) o[ct][r] *= alpha;

            // ---- P store: 4 keys contiguous per tile -> 4x b64 ------------
#pragma unroll
            for (int t = 0; t < 4; ++t) {
                half4 w;
#pragma unroll
                for (int r = 0; r < 4; ++r) w[r] = (_Float16)p[t][r];
                *(half4*)&Pb[wave][l16][t * 16 + quad * 4] = w;
            }
            // B-operand read-back: row q, 8 consecutive keys (same wave,
            // in-order DS -> no barrier needed)
            half8 pb0 = *(const half8*)&Pb[wave][l16][quad * 8];
            half8 pb1 = *(const half8*)&Pb[wave][l16][32 + quad * 8];

            // ---- O^T += V^T P^T -------------------------------------------
#pragma unroll
            for (int ct = 0; ct < 4; ++ct) {
                half8 va0 = *(const half8*)&Vt[ct * 16 + l16][quad * 8];
                half8 va1 = *(const half8*)&Vt[ct * 16 + l16][32 + quad * 8];
                o[ct] = __builtin_amdgcn_mfma_f32_16x16x32_f16(va0, pb0, o[ct], 0, 0, 0);
                o[ct] = __builtin_amdgcn_mfma_f32_16x16x32_f16(va1, pb1, o[ct], 0, 0, 0);
            }
        } // kb

        // ---- epilogue: O^T[d][q] / l -> resh[q][d], half4 packed ----------
        const float inv = 1.0f / l_r;
#pragma unroll
        for (int ct = 0; ct < 4; ++ct) {
            half4 w;
#pragma unroll
            for (int r = 0; r < 4; ++r) w[r] = (_Float16)(o[ct][r] * inv);
            *(half4*)&resh[(size_t)(q0 + l16) * EMB + h * HDIM + ct * 16 + quad * 4] = w;
        }
    } // half
}

// ---------------------------------------------------------------------------
// launch
// ---------------------------------------------------------------------------
extern "C" void kernel_launch(void* const* d_in, const int* in_sizes, int n_in,
                              void* d_out, int out_size, void* d_ws, size_t ws_size,
                              hipStream_t stream)
{
    const float* x    = (const float*)d_in[0];
    const float* Wqkv = (const float*)d_in[2];
    const float* bqkv = (const float*)d_in[3];
    const float* Wp   = (const float*)d_in[4];
    const float* bp   = (const float*)d_in[5];
    float* out = (float*)d_out;

    _Float16* xh  = (_Float16*)d_ws;                 // [4096,1024] fp16
    _Float16* WTh = xh + (size_t)4096 * 1024;        // [3072,1024] fp16
    _Float16* qkh = WTh + (size_t)3072 * 1024;       // [4096,2048] fp16
    _Float16* vtg = qkh + (size_t)4096 * 2048;       // V^T [1024,4096] fp16
    _Float16* resh = xh;            // alias: x fp16 dead after QKV GEMM
    _Float16* WpT  = WTh;           // alias: Wqkv^T dead after QKV GEMM

    dim3 blk(256);

    convert_f16<<<4096, blk, 0, stream>>>(x, xh);
    transpose_f16<<<dim3(3072 / 64, 1024 / 64), blk, 0, stream>>>(
        Wqkv, WTh, 1024, 3072);

    gemm_qkv<<<dim3(3072 / 128, 4096 / 128), blk, 0, stream>>>(
        xh, WTh, bqkv, qkh, vtg, 1024);

    transpose_f16<<<dim3(1024 / 64, 1024 / 64), blk, 0, stream>>>(
        Wp, WpT, 1024, 1024);

    flash_attn_f16<<<dim3(1024), dim3(128), 0, stream>>>(qkh, vtg, resh);

    gemm_out<<<dim3(1024 / 128, 4096 / 128), blk, 0, stream>>>(
        resh, WpT, bp, out, 1024, 1024);
}